// Round 2
// baseline (528.948 us; speedup 1.0000x reference)
//
#include <hip/hip_runtime.h>
#include <hip/hip_bf16.h>

#define KDIM 512
#define NDIM 512
#define ATT  196
#define NB   1024

typedef __attribute__((ext_vector_type(8))) short bf16x8;
typedef __attribute__((ext_vector_type(8))) unsigned short ushort8;
typedef __attribute__((ext_vector_type(4))) float f32x4;

typedef const __attribute__((address_space(1))) unsigned int gas_uint;
typedef __attribute__((address_space(3))) unsigned int las_uint;

__device__ __forceinline__ void gload16(const void* g, void* l) {
    __builtin_amdgcn_global_load_lds((gas_uint*)g, (las_uint*)l, 16, 0, 0);
}

__device__ __forceinline__ float fast_tanh(float x) {
    x = fminf(15.f, fmaxf(-15.f, x));
    float t = __expf(2.f * x);
    return (t - 1.f) / (t + 1.f);
}

__device__ __forceinline__ unsigned short f2bf(float x) {
    union { float f; unsigned u; } v; v.f = x;
    unsigned r = v.u + 0x7FFF + ((v.u >> 16) & 1);   // RNE
    return (unsigned short)(r >> 16);
}

__device__ __forceinline__ unsigned pk2(float a, float b) {
    __hip_bfloat162 h = __float22bfloat162_rn(float2{a, b});
    union { __hip_bfloat162 h2; unsigned u; } c; c.h2 = h;
    return c.u;
}

// ---------------------------------------------------------------------------
// Transpose+cast 6 weights: W[k][n] f32 -> Wt[n][k] bf16 (row-major n-major),
// so GEMM B-staging can global_load_lds contiguous 16B chunks of k.
// grid = 6 weights * 64 tiles of 64x64, 256 threads.
// ---------------------------------------------------------------------------
__global__ __launch_bounds__(256) void prep_weights(
        const float* __restrict__ W0, const float* __restrict__ W1,
        const float* __restrict__ W2, const float* __restrict__ W3,
        const float* __restrict__ W4, const float* __restrict__ W5,
        unsigned short* __restrict__ Wt) {
    int w = blockIdx.x >> 6;
    int t = blockIdx.x & 63;
    int k0 = (t >> 3) << 6, n0 = (t & 7) << 6;
    const float* W = (w == 0) ? W0 : (w == 1) ? W1 : (w == 2) ? W2 :
                     (w == 3) ? W3 : (w == 4) ? W4 : W5;
    __shared__ float tile[64][65];
    int tid = threadIdx.x;
    int nc = tid & 15, kr = tid >> 4;
#pragma unroll
    for (int i = 0; i < 4; ++i) {
        int k = kr + i * 16;
        float4 v = *(const float4*)&W[(size_t)(k0 + k) * NDIM + n0 + nc * 4];
        tile[k][nc * 4 + 0] = v.x; tile[k][nc * 4 + 1] = v.y;
        tile[k][nc * 4 + 2] = v.z; tile[k][nc * 4 + 3] = v.w;
    }
    __syncthreads();
    int n = tid >> 2, ks = tid & 3;
    ushort8 v0, v1;
#pragma unroll
    for (int j = 0; j < 8; ++j) v0[j] = f2bf(tile[ks * 16 + j][n]);
#pragma unroll
    for (int j = 0; j < 8; ++j) v1[j] = f2bf(tile[ks * 16 + 8 + j][n]);
    size_t base = ((size_t)w << 18) + (size_t)(n0 + n) * KDIM + k0 + ks * 16;
    *(ushort8*)&Wt[base] = v0;
    *(ushort8*)&Wt[base + 8] = v1;
}

// ---------------------------------------------------------------------------
// GEMM: C[M,512] = A[M,512](f32) @ Wt^T (Wt is [n][k] bf16).
// BM=BN=128, BK=32, 256 threads = 4 waves (2M x 2N), wave tile 64x64.
// A: f32 -> cvt_pk bf16 -> ds_write_b128 (XOR-swizzled slots).
// B: global_load_lds 16B, swizzle baked into per-lane source address.
// Grid = MPX*32, XCD-grouped: b -> xcd=b&7, same-mtile nblk siblings adjacent
// on one XCD (A-tile L2 reuse).
// EPI_SCORE: atomicAdd per-row partial of sum_col tanh(acc+bias+h_emb)*Walpha.
// ---------------------------------------------------------------------------
#define EPI_RELU  0
#define EPI_TANH  1
#define EPI_NONE  2
#define EPI_SCORE 3

template<int EPI, int DIVR, int ADDI, int MPX>
__launch_bounds__(256, 3)
__global__ void gemm128(const float* __restrict__ A, const unsigned short* __restrict__ Bt,
                        const float* __restrict__ bias, float* __restrict__ out,
                        const float* __restrict__ h_emb, const float* __restrict__ Walpha) {
    __shared__ unsigned short A_lds[2][128 * 32];
    __shared__ unsigned short B_lds[2][128 * 32];
    __shared__ float s_red[2][128];

    const int tid  = threadIdx.x;
    const int bidx = blockIdx.x;
    const int xcd  = bidx & 7, u = bidx >> 3;
    const int mblk = xcd * MPX + (u >> 2), nblk = u & 3;
    const int gm0  = mblk * 128, gn0 = nblk * 128;

    const int wid = tid >> 6, lane = tid & 63;
    const int wm  = wid >> 1, wn = wid & 1;
    const int lr  = lane & 15, lk = lane >> 4;

    // A staging: thread -> row=tid>>1, half=tid&1 (16 f32 -> 2 bf16 chunks)
    const int arow = tid >> 1, ahalf = tid & 1;
    const float* aptr = A + (size_t)(gm0 + arow) * KDIM + ahalf * 16;
    const int akcp0 = (ahalf * 2) ^ (arow & 3);
    const int aoff0 = arow * 32 + akcp0 * 8;
    const int aoff1 = arow * 32 + (akcp0 ^ 1) * 8;

    // B staging: chunk c -> col=c>>2, slot kcp=c&3 holds source kc=kcp^(col&3)
    const int c1 = tid + 256;
    const int bcol0 = tid >> 2, bk0 = (tid & 3) ^ (bcol0 & 3);
    const int bcol1 = c1 >> 2,  bk1 = (c1 & 3) ^ (bcol1 & 3);
    const unsigned short* bsrc0 = Bt + (size_t)(gn0 + bcol0) * KDIM + bk0 * 8;
    const unsigned short* bsrc1 = Bt + (size_t)(gn0 + bcol1) * KDIM + bk1 * 8;

    f32x4 acc[4][4] = {};

    auto stage = [&](int kt, int buf) {
        gload16(bsrc0 + kt * 32, &B_lds[buf][tid * 8]);
        gload16(bsrc1 + kt * 32, &B_lds[buf][c1 * 8]);
        const float* ap = aptr + kt * 32;
        float4 f0 = *(const float4*)(ap);
        float4 f1 = *(const float4*)(ap + 4);
        float4 f2 = *(const float4*)(ap + 8);
        float4 f3 = *(const float4*)(ap + 12);
        uint4 p0, p1;
        p0.x = pk2(f0.x, f0.y); p0.y = pk2(f0.z, f0.w);
        p0.z = pk2(f1.x, f1.y); p0.w = pk2(f1.z, f1.w);
        p1.x = pk2(f2.x, f2.y); p1.y = pk2(f2.z, f2.w);
        p1.z = pk2(f3.x, f3.y); p1.w = pk2(f3.z, f3.w);
        *(uint4*)&A_lds[buf][aoff0] = p0;
        *(uint4*)&A_lds[buf][aoff1] = p1;
    };

    stage(0, 0);
    __syncthreads();

    const int swk = ((lk ^ (lr & 3)) << 3);
    for (int kt = 0; kt < 16; ++kt) {
        const int buf = kt & 1;
        if (kt < 15) stage(kt + 1, buf ^ 1);
        bf16x8 af[4], bfr[4];
#pragma unroll
        for (int m = 0; m < 4; ++m)
            af[m] = *(const bf16x8*)&A_lds[buf][(wm * 64 + m * 16 + lr) * 32 + swk];
#pragma unroll
        for (int n = 0; n < 4; ++n)
            bfr[n] = *(const bf16x8*)&B_lds[buf][(wn * 64 + n * 16 + lr) * 32 + swk];
#pragma unroll
        for (int m = 0; m < 4; ++m)
#pragma unroll
            for (int n = 0; n < 4; ++n)
                acc[m][n] = __builtin_amdgcn_mfma_f32_16x16x32_bf16(af[m], bfr[n], acc[m][n], 0, 0, 0);
        __syncthreads();
    }

    if constexpr (EPI == EPI_SCORE) {
        float wa[4], bs[4];
        int cols[4];
#pragma unroll
        for (int n = 0; n < 4; ++n) {
            cols[n] = gn0 + wn * 64 + n * 16 + lr;
            bs[n] = bias[cols[n]];
            wa[n] = Walpha[cols[n]];
        }
#pragma unroll
        for (int m = 0; m < 4; ++m) {
#pragma unroll
            for (int r = 0; r < 4; ++r) {
                int rloc = wm * 64 + m * 16 + lk * 4 + r;
                int rg = gm0 + rloc;
                int bb = rg / DIVR;
                const float* he = h_emb + (size_t)bb * NDIM;
                float sum = 0.f;
#pragma unroll
                for (int n = 0; n < 4; ++n)
                    sum += fast_tanh(acc[m][n][r] + bs[n] + he[cols[n]]) * wa[n];
                sum += __shfl_xor(sum, 1);
                sum += __shfl_xor(sum, 2);
                sum += __shfl_xor(sum, 4);
                sum += __shfl_xor(sum, 8);
                if (lr == 0) s_red[wn][rloc] = sum;
            }
        }
        __syncthreads();
        if (tid < 128) {
            float tot = s_red[0][tid] + s_red[1][tid];
            int rg = gm0 + tid;
            int bb = rg / DIVR;
            atomicAdd(&out[(size_t)bb * 197 + (rg - bb * DIVR) + ADDI], tot);
        }
    } else {
#pragma unroll
        for (int m = 0; m < 4; ++m)
#pragma unroll
            for (int n = 0; n < 4; ++n) {
                int col = gn0 + wn * 64 + n * 16 + lr;
#pragma unroll
                for (int r = 0; r < 4; ++r) {
                    int row = gm0 + wm * 64 + m * 16 + lk * 4 + r;
                    float v = acc[m][n][r] + bias[col];
                    if constexpr (EPI == EPI_RELU) v = fmaxf(v, 0.f);
                    if constexpr (EPI == EPI_TANH) v = fast_tanh(v);
                    out[(size_t)row * NDIM + col] = v;
                }
            }
    }
}

// ---------------------------------------------------------------------------
// Per-batch: softmax over 197 scores, then
// atten_out[b,:] = alpha0*sent_lin[b,:] + sum_s alpha[s+1]*att[b,s,:] + h_lin[b,:]
// ---------------------------------------------------------------------------
__global__ __launch_bounds__(256) void softmax_chat(
        const float* __restrict__ score, const float* __restrict__ sent_lin,
        const float* __restrict__ h_lin, const float* __restrict__ att,
        float* __restrict__ atten_out) {
    int b = blockIdx.x, tid = threadIdx.x;
    __shared__ float al[200];
    __shared__ float rmax[4], rsum[4];

    float v = (tid < 197) ? score[b * 197 + tid] : -1e30f;
    float m = v;
#pragma unroll
    for (int o = 32; o; o >>= 1) m = fmaxf(m, __shfl_xor(m, o));
    if ((tid & 63) == 0) rmax[tid >> 6] = m;
    __syncthreads();
    m = fmaxf(fmaxf(rmax[0], rmax[1]), fmaxf(rmax[2], rmax[3]));
    float e = (tid < 197) ? __expf(v - m) : 0.f;
    float s = e;
#pragma unroll
    for (int o = 32; o; o >>= 1) s += __shfl_xor(s, o);
    if ((tid & 63) == 0) rsum[tid >> 6] = s;
    __syncthreads();
    s = rsum[0] + rsum[1] + rsum[2] + rsum[3];
    if (tid < 197) al[tid] = e / s;
    __syncthreads();

    const float2* af = (const float2*)(att + (size_t)b * ATT * KDIM);
    float2 a0 = ((const float2*)(sent_lin + (size_t)b * KDIM))[tid];
    float w0 = al[0];
    float2 accv; accv.x = w0 * a0.x; accv.y = w0 * a0.y;
#pragma unroll 4
    for (int ss = 0; ss < ATT; ++ss) {
        float w = al[ss + 1];
        float2 x = af[(size_t)ss * 256 + tid];
        accv.x += w * x.x; accv.y += w * x.y;
    }
    float2 hl = ((const float2*)(h_lin + (size_t)b * KDIM))[tid];
    accv.x += hl.x; accv.y += hl.y;
    ((float2*)(atten_out + (size_t)b * KDIM))[tid] = accv;
}

// ---------------------------------------------------------------------------
extern "C" void kernel_launch(void* const* d_in, const int* in_sizes, int n_in,
                              void* d_out, int out_size, void* d_ws, size_t ws_size,
                              hipStream_t stream) {
    const float* h     = (const float*)d_in[0];
    const float* sent  = (const float*)d_in[1];
    const float* att   = (const float*)d_in[2];
    const float* W_ctx = (const float*)d_in[3];
    const float* b_ctx = (const float*)d_in[4];
    const float* W_sl  = (const float*)d_in[5];
    const float* b_sl  = (const float*)d_in[6];
    const float* W_se  = (const float*)d_in[7];
    const float* b_se  = (const float*)d_in[8];
    const float* W_hl  = (const float*)d_in[9];
    const float* b_hl  = (const float*)d_in[10];
    const float* W_he  = (const float*)d_in[11];
    const float* b_he  = (const float*)d_in[12];
    const float* W_al  = (const float*)d_in[13];
    // d_in[14] = b_alpha: constant shift across positions, cancels in softmax
    const float* W_a2h = (const float*)d_in[15];
    const float* b_a2h = (const float*)d_in[16];
    float* out = (float*)d_out;

    char* ws = (char*)d_ws;
    unsigned short* Wt = (unsigned short*)ws;                 // 6 * 512KB bf16 = 3MB
    float* sent_lin = (float*)(ws + 6u * 512 * 1024);
    float* h_lin    = sent_lin + (size_t)NB * 512;
    float* h_emb    = h_lin    + (size_t)NB * 512;
    float* scorebuf = h_emb    + (size_t)NB * 512;            // 1024*197
    float* atten    = scorebuf + (size_t)NB * 197;

    const size_t WSZ = 512 * 512;  // ushorts per weight
    // weight order in Wt: 0=W_sl 1=W_hl 2=W_he 3=W_ctx 4=W_a2h 5=W_se
    prep_weights<<<384, 256, 0, stream>>>(W_sl, W_hl, W_he, W_ctx, W_a2h, W_se, Wt);
    hipMemsetAsync(scorebuf, 0, (size_t)NB * 197 * sizeof(float), stream);

    gemm128<EPI_RELU, 1, 0, 1><<<32, 256, 0, stream>>>(sent, Wt + 0 * WSZ, b_sl, sent_lin, nullptr, nullptr);
    gemm128<EPI_TANH, 1, 0, 1><<<32, 256, 0, stream>>>(h,    Wt + 1 * WSZ, b_hl, h_lin,    nullptr, nullptr);
    gemm128<EPI_NONE, 1, 0, 1><<<32, 256, 0, stream>>>(h_lin, Wt + 2 * WSZ, b_he, h_emb,   nullptr, nullptr);
    // sentinel score -> scorebuf[b*197 + 0]
    gemm128<EPI_SCORE, 1, 0, 1><<<32, 256, 0, stream>>>(sent_lin, Wt + 5 * WSZ, b_se, scorebuf, h_emb, W_al);
    // visual scores -> scorebuf[b*197 + 1 + s]   (M = 200704 rows, 1568 mtiles)
    gemm128<EPI_SCORE, 196, 1, 196><<<6272, 256, 0, stream>>>(att, Wt + 3 * WSZ, b_ctx, scorebuf, h_emb, W_al);

    softmax_chat<<<NB, 256, 0, stream>>>(scorebuf, sent_lin, h_lin, att, atten);

    gemm128<EPI_TANH, 1, 0, 1><<<32, 256, 0, stream>>>(atten, Wt + 4 * WSZ, b_a2h, out, nullptr, nullptr);
}

// Round 3
// 520.987 us; speedup vs baseline: 1.0153x; 1.0153x over previous
//
#include <hip/hip_runtime.h>
#include <hip/hip_bf16.h>

#define KDIM 512
#define NDIM 512
#define ATT  196
#define NB   1024

typedef __attribute__((ext_vector_type(8))) short bf16x8;
typedef __attribute__((ext_vector_type(8))) unsigned short ushort8;
typedef __attribute__((ext_vector_type(4))) float f32x4;

typedef const __attribute__((address_space(1))) unsigned int gas_uint;
typedef __attribute__((address_space(3))) unsigned int las_uint;

__device__ __forceinline__ void gload16(const void* g, void* l) {
    __builtin_amdgcn_global_load_lds((gas_uint*)g, (las_uint*)l, 16, 0, 0);
}

__device__ __forceinline__ float fast_tanh(float x) {
    x = fminf(15.f, fmaxf(-15.f, x));
    float t = __expf(2.f * x);
    return (t - 1.f) / (t + 1.f);
}

__device__ __forceinline__ unsigned short f2bf(float x) {
    union { float f; unsigned u; } v; v.f = x;
    unsigned r = v.u + 0x7FFF + ((v.u >> 16) & 1);   // RNE
    return (unsigned short)(r >> 16);
}

__device__ __forceinline__ unsigned pk2(float a, float b) {
    __hip_bfloat162 h = __float22bfloat162_rn(float2{a, b});
    union { __hip_bfloat162 h2; unsigned u; } c; c.h2 = h;
    return c.u;
}

// ---------------------------------------------------------------------------
// Transpose+cast 6 weights: W[k][n] f32 -> Wt[n][k] bf16 ([n][k] row-major).
// ---------------------------------------------------------------------------
__global__ __launch_bounds__(256) void prep_weights(
        const float* __restrict__ W0, const float* __restrict__ W1,
        const float* __restrict__ W2, const float* __restrict__ W3,
        const float* __restrict__ W4, const float* __restrict__ W5,
        unsigned short* __restrict__ Wt) {
    int w = blockIdx.x >> 6;
    int t = blockIdx.x & 63;
    int k0 = (t >> 3) << 6, n0 = (t & 7) << 6;
    const float* W = (w == 0) ? W0 : (w == 1) ? W1 : (w == 2) ? W2 :
                     (w == 3) ? W3 : (w == 4) ? W4 : W5;
    __shared__ float tile[64][65];
    int tid = threadIdx.x;
    int nc = tid & 15, kr = tid >> 4;
#pragma unroll
    for (int i = 0; i < 4; ++i) {
        int k = kr + i * 16;
        float4 v = *(const float4*)&W[(size_t)(k0 + k) * NDIM + n0 + nc * 4];
        tile[k][nc * 4 + 0] = v.x; tile[k][nc * 4 + 1] = v.y;
        tile[k][nc * 4 + 2] = v.z; tile[k][nc * 4 + 3] = v.w;
    }
    __syncthreads();
    int n = tid >> 2, ks = tid & 3;
    ushort8 v0, v1;
#pragma unroll
    for (int j = 0; j < 8; ++j) v0[j] = f2bf(tile[ks * 16 + j][n]);
#pragma unroll
    for (int j = 0; j < 8; ++j) v1[j] = f2bf(tile[ks * 16 + 8 + j][n]);
    size_t base = ((size_t)w << 18) + (size_t)(n0 + n) * KDIM + k0 + ks * 16;
    *(ushort8*)&Wt[base] = v0;
    *(ushort8*)&Wt[base + 8] = v1;
}

// ---------------------------------------------------------------------------
// Small GEMM: out = act(A[1024,512] @ Wt^T + bias). BM=64, BN=128,
// 256 thr = 4 waves (2Mx2N), wave 32x64, acc 2x4. T14 pipeline, fixed swizzle.
// Two independent ops batched via blockIdx.y.
// act: 0=relu 1=tanh 2=none
// ---------------------------------------------------------------------------
__global__ __launch_bounds__(256) void gemm64(
        const float* __restrict__ A0, const unsigned short* __restrict__ W0,
        const float* __restrict__ bia0, float* __restrict__ O0, int act0,
        const float* __restrict__ A1, const unsigned short* __restrict__ W1,
        const float* __restrict__ bia1, float* __restrict__ O1, int act1) {
    const int op = blockIdx.y;
    const float* A = op ? A1 : A0;
    const unsigned short* Bt = op ? W1 : W0;
    const float* bias = op ? bia1 : bia0;
    float* out = op ? O1 : O0;
    const int act = op ? act1 : act0;

    __shared__ unsigned short A_lds[2][64 * 32];
    __shared__ unsigned short B_lds[2][128 * 32];

    const int tid = threadIdx.x;
    const int gm0 = (blockIdx.x >> 2) * 64, gn0 = (blockIdx.x & 3) * 128;
    const int wid = tid >> 6, lane = tid & 63;
    const int wm = wid >> 1, wn = wid & 1;
    const int lr = lane & 15, lk = lane >> 4;

    // A staging: thread -> chunk c=tid: row=c>>2, kc=c&3
    const int arow = tid >> 2, akc = tid & 3;
    const float* aptr = A + (size_t)(gm0 + arow) * KDIM + akc * 8;
    const int aoff = arow * 32 + ((akc ^ ((arow >> 1) & 3)) << 3);

    // B staging: chunks c=tid, tid+256: col=c>>2, slot=c&3, src kc=slot^((col>>1)&3)
    auto stageB = [&](int kt, int buf) {
#pragma unroll
        for (int j = 0; j < 2; ++j) {
            int c = tid + j * 256;
            int col = c >> 2, slot = c & 3;
            const unsigned short* src = Bt + (size_t)(gn0 + col) * KDIM +
                                        ((slot ^ ((col >> 1) & 3)) << 3) + kt * 32;
            gload16(src, &B_lds[buf][c * 8]);
        }
    };

    f32x4 acc[2][4] = {};

    // prologue: stage kt=0
    {
        float4 x0 = *(const float4*)aptr;
        float4 x1 = *(const float4*)(aptr + 4);
        stageB(0, 0);
        uint4 p;
        p.x = pk2(x0.x, x0.y); p.y = pk2(x0.z, x0.w);
        p.z = pk2(x1.x, x1.y); p.w = pk2(x1.z, x1.w);
        *(uint4*)&A_lds[0][aoff] = p;
    }
    __syncthreads();

    const int swk = ((lk ^ ((lr >> 1) & 3)) << 3);
    for (int kt = 0; kt < 16; ++kt) {
        const int buf = kt & 1;
        float4 x0, x1;
        if (kt < 15) {
            const float* ap = aptr + (kt + 1) * 32;
            x0 = *(const float4*)ap;
            x1 = *(const float4*)(ap + 4);
            stageB(kt + 1, buf ^ 1);
        }
        bf16x8 af[2], bfr[4];
#pragma unroll
        for (int m = 0; m < 2; ++m)
            af[m] = *(const bf16x8*)&A_lds[buf][(wm * 32 + m * 16 + lr) * 32 + swk];
#pragma unroll
        for (int n = 0; n < 4; ++n)
            bfr[n] = *(const bf16x8*)&B_lds[buf][(wn * 64 + n * 16 + lr) * 32 + swk];
#pragma unroll
        for (int m = 0; m < 2; ++m)
#pragma unroll
            for (int n = 0; n < 4; ++n)
                acc[m][n] = __builtin_amdgcn_mfma_f32_16x16x32_bf16(af[m], bfr[n], acc[m][n], 0, 0, 0);
        if (kt < 15) {
            uint4 p;
            p.x = pk2(x0.x, x0.y); p.y = pk2(x0.z, x0.w);
            p.z = pk2(x1.x, x1.y); p.w = pk2(x1.z, x1.w);
            *(uint4*)&A_lds[buf ^ 1][aoff] = p;
        }
        __syncthreads();
    }

#pragma unroll
    for (int m = 0; m < 2; ++m)
#pragma unroll
        for (int n = 0; n < 4; ++n) {
            int col = gn0 + wn * 64 + n * 16 + lr;
            float bsv = bias[col];
#pragma unroll
            for (int r = 0; r < 4; ++r) {
                int row = gm0 + wm * 32 + m * 16 + lk * 4 + r;
                float v = acc[m][n][r] + bsv;
                if (act == 0) v = fmaxf(v, 0.f);
                else if (act == 1) v = fast_tanh(v);
                out[(size_t)row * NDIM + col] = v;
            }
        }
}

// ---------------------------------------------------------------------------
// Fused per-batch kernel: one block per batch b (512 thr = 8 waves).
//  1. prologue: ch_s = b_ctx + h_emb[b]; sentinel score from sent_emb+h_emb
//  2. scores GEMM: att[b](196 rows, pad 224) @ W_ctx^T in two 112-row chunks;
//     8 waves = 1M x 8N, wave tile 112x64, acc 7x4. T14 pipeline.
//     epilogue: score[row] = sum_col tanh(acc + ch_s[col]) * Walpha[col]
//  3. softmax over 197 (sentinel + 196)
//  4. context: atten[b,c] = al0*sent_lin + sum_s al[s+1]*att[b,s,c] + h_lin
// ---------------------------------------------------------------------------
__global__ __launch_bounds__(512, 2) void fused_att(
        const float* __restrict__ att, const unsigned short* __restrict__ Bt,
        const float* __restrict__ sent_emb, const float* __restrict__ h_emb,
        const float* __restrict__ sent_lin, const float* __restrict__ h_lin,
        const float* __restrict__ b_ctx, const float* __restrict__ Walpha,
        float* __restrict__ atten) {
    __shared__ unsigned short A_lds[2][112 * 32];
    __shared__ unsigned short B_lds[2][512 * 32];
    __shared__ float ch_s[512];
    __shared__ float wa_s[512];
    __shared__ float red[8][112];
    __shared__ float scores_s[224];
    __shared__ float al_s[200];
    __shared__ float wr8[8];
    __shared__ float ssent_s;

    const int tid = threadIdx.x;
    const int b = blockIdx.x;
    const int wid = tid >> 6, lane = tid & 63;
    const int lr = lane & 15, lk = lane >> 4;

    // ---- prologue: ch_s, wa_s, sentinel score partial ----
    {
        float he = h_emb[(size_t)b * NDIM + tid];
        float se = sent_emb[(size_t)b * NDIM + tid];
        float wa = Walpha[tid];
        ch_s[tid] = b_ctx[tid] + he;
        wa_s[tid] = wa;
        float val = fast_tanh(se + he) * wa;
#pragma unroll
        for (int o = 32; o; o >>= 1) val += __shfl_xor(val, o);
        if (lane == 0) wr8[wid] = val;
    }
    __syncthreads();
    if (tid == 0) {
        float s = 0.f;
#pragma unroll
        for (int w = 0; w < 8; ++w) s += wr8[w];
        ssent_s = s;
    }

    // ---- staging constants ----
    const int arow = tid >> 2, akc = tid & 3;           // threads 0..447 stage A
    const int aoff = arow * 32 + ((akc ^ ((arow >> 1) & 3)) << 3);
    const float* attb = att + (size_t)b * ATT * KDIM;

    auto stageB = [&](int kt, int buf) {
#pragma unroll
        for (int j = 0; j < 4; ++j) {
            int c = tid + j * 512;
            int col = c >> 2, slot = c & 3;
            const unsigned short* src = Bt + (size_t)col * KDIM +
                                        ((slot ^ ((col >> 1) & 3)) << 3) + kt * 32;
            gload16(src, &B_lds[buf][c * 8]);
        }
    };

    const int swk = ((lk ^ ((lr >> 1) & 3)) << 3);

#pragma unroll 1
    for (int mc = 0; mc < 2; ++mc) {
        f32x4 acc[7][4];
#pragma unroll
        for (int m = 0; m < 7; ++m)
#pragma unroll
            for (int n = 0; n < 4; ++n)
                acc[m][n] = (f32x4){0.f, 0.f, 0.f, 0.f};

        const int rowg = mc * 112 + arow;
        const bool doA = (tid < 448) && (rowg < ATT);
        const float* ap0 = attb + (size_t)rowg * KDIM + akc * 8;

        // prologue stage kt=0
        {
            float4 x0{0,0,0,0}, x1{0,0,0,0};
            if (doA) { x0 = *(const float4*)ap0; x1 = *(const float4*)(ap0 + 4); }
            stageB(0, 0);
            if (tid < 448) {
                uint4 p;
                p.x = pk2(x0.x, x0.y); p.y = pk2(x0.z, x0.w);
                p.z = pk2(x1.x, x1.y); p.w = pk2(x1.z, x1.w);
                *(uint4*)&A_lds[0][aoff] = p;
            }
        }
        __syncthreads();

        for (int kt = 0; kt < 16; ++kt) {
            const int buf = kt & 1;
            float4 x0{0,0,0,0}, x1{0,0,0,0};
            if (kt < 15) {
                if (doA) {
                    const float* ap = ap0 + (kt + 1) * 32;
                    x0 = *(const float4*)ap;
                    x1 = *(const float4*)(ap + 4);
                }
                stageB(kt + 1, buf ^ 1);
            }
            bf16x8 af[7], bfr[4];
#pragma unroll
            for (int m = 0; m < 7; ++m)
                af[m] = *(const bf16x8*)&A_lds[buf][(m * 16 + lr) * 32 + swk];
#pragma unroll
            for (int n = 0; n < 4; ++n)
                bfr[n] = *(const bf16x8*)&B_lds[buf][(wid * 64 + n * 16 + lr) * 32 + swk];
#pragma unroll
            for (int m = 0; m < 7; ++m)
#pragma unroll
                for (int n = 0; n < 4; ++n)
                    acc[m][n] = __builtin_amdgcn_mfma_f32_16x16x32_bf16(af[m], bfr[n], acc[m][n], 0, 0, 0);
            if (kt < 15 && tid < 448) {
                uint4 p;
                p.x = pk2(x0.x, x0.y); p.y = pk2(x0.z, x0.w);
                p.z = pk2(x1.x, x1.y); p.w = pk2(x1.z, x1.w);
                *(uint4*)&A_lds[buf ^ 1][aoff] = p;
            }
            __syncthreads();
        }

        // ---- score epilogue for this chunk ----
        float chv[4], wav[4];
#pragma unroll
        for (int n = 0; n < 4; ++n) {
            int col = wid * 64 + n * 16 + lr;
            chv[n] = ch_s[col];
            wav[n] = wa_s[col];
        }
#pragma unroll
        for (int m = 0; m < 7; ++m) {
#pragma unroll
            for (int r = 0; r < 4; ++r) {
                int row = m * 16 + lk * 4 + r;
                float sum = 0.f;
#pragma unroll
                for (int n = 0; n < 4; ++n)
                    sum += fast_tanh(acc[m][n][r] + chv[n]) * wav[n];
                sum += __shfl_xor(sum, 1);
                sum += __shfl_xor(sum, 2);
                sum += __shfl_xor(sum, 4);
                sum += __shfl_xor(sum, 8);
                if (lr == 0) red[wid][row] = sum;
            }
        }
        __syncthreads();
        if (tid < 112) {
            float s = 0.f;
#pragma unroll
            for (int w = 0; w < 8; ++w) s += red[w][tid];
            scores_s[mc * 112 + tid] = s;
        }
        __syncthreads();
    }

    // ---- softmax over 197 ----
    float v = -1e30f;
    if (tid < 197) v = (tid == 0) ? ssent_s : scores_s[tid - 1];
    float mx = v;
#pragma unroll
    for (int o = 32; o; o >>= 1) mx = fmaxf(mx, __shfl_xor(mx, o));
    if (lane == 0) wr8[wid] = mx;
    __syncthreads();
    mx = wr8[0];
#pragma unroll
    for (int w = 1; w < 8; ++w) mx = fmaxf(mx, wr8[w]);
    float e = (tid < 197) ? __expf(v - mx) : 0.f;
    float sm = e;
#pragma unroll
    for (int o = 32; o; o >>= 1) sm += __shfl_xor(sm, o);
    __syncthreads();
    if (lane == 0) wr8[wid] = sm;
    __syncthreads();
    float S = 0.f;
#pragma unroll
    for (int w = 0; w < 8; ++w) S += wr8[w];
    if (tid < 197) al_s[tid] = e / S;
    __syncthreads();

    // ---- context: one column per thread ----
    float accv = al_s[0] * sent_lin[(size_t)b * NDIM + tid] +
                 h_lin[(size_t)b * NDIM + tid];
    const float* arow_p = attb + tid;
#pragma unroll 14
    for (int s = 0; s < ATT; ++s)
        accv += al_s[s + 1] * arow_p[(size_t)s * KDIM];
    atten[(size_t)b * NDIM + tid] = accv;
}

// ---------------------------------------------------------------------------
extern "C" void kernel_launch(void* const* d_in, const int* in_sizes, int n_in,
                              void* d_out, int out_size, void* d_ws, size_t ws_size,
                              hipStream_t stream) {
    const float* h     = (const float*)d_in[0];
    const float* sent  = (const float*)d_in[1];
    const float* att   = (const float*)d_in[2];
    const float* W_ctx = (const float*)d_in[3];
    const float* b_ctx = (const float*)d_in[4];
    const float* W_sl  = (const float*)d_in[5];
    const float* b_sl  = (const float*)d_in[6];
    const float* W_se  = (const float*)d_in[7];
    const float* b_se  = (const float*)d_in[8];
    const float* W_hl  = (const float*)d_in[9];
    const float* b_hl  = (const float*)d_in[10];
    const float* W_he  = (const float*)d_in[11];
    const float* b_he  = (const float*)d_in[12];
    const float* W_al  = (const float*)d_in[13];
    // d_in[14] = b_alpha: constant across positions, cancels in softmax
    const float* W_a2h = (const float*)d_in[15];
    const float* b_a2h = (const float*)d_in[16];
    float* out = (float*)d_out;

    char* ws = (char*)d_ws;
    unsigned short* Wt = (unsigned short*)ws;                 // 6 * 512KB bf16 = 3MB
    float* sent_lin = (float*)(ws + 6u * 512 * 1024);
    float* h_lin    = sent_lin + (size_t)NB * 512;
    float* h_emb    = h_lin    + (size_t)NB * 512;
    float* sent_emb = h_emb    + (size_t)NB * 512;
    float* atten    = sent_emb + (size_t)NB * 512;

    const size_t WSZ = 512 * 512;  // ushorts per weight
    // Wt order: 0=W_sl 1=W_hl 2=W_he 3=W_ctx 4=W_a2h 5=W_se
    prep_weights<<<384, 256, 0, stream>>>(W_sl, W_hl, W_he, W_ctx, W_a2h, W_se, Wt);

    // sent_lin = relu(sent@W_sl+b_sl); h_lin = tanh(h@W_hl+b_hl)
    gemm64<<<dim3(64, 2), 256, 0, stream>>>(
        sent, Wt + 0 * WSZ, b_sl, sent_lin, 0,
        h,    Wt + 1 * WSZ, b_hl, h_lin,    1);
    // h_emb = h_lin@W_he+b_he; sent_emb = sent_lin@W_se+b_se
    gemm64<<<dim3(64, 2), 256, 0, stream>>>(
        h_lin,    Wt + 2 * WSZ, b_he, h_emb,    2,
        sent_lin, Wt + 5 * WSZ, b_se, sent_emb, 2);

    fused_att<<<NB, 512, 0, stream>>>(att, Wt + 3 * WSZ, sent_emb, h_emb,
                                      sent_lin, h_lin, b_ctx, W_al, atten);

    // out = tanh(atten@W_a2h + b_a2h)
    gemm64<<<dim3(64, 1), 256, 0, stream>>>(
        atten, Wt + 4 * WSZ, b_a2h, out, 1,
        atten, Wt + 4 * WSZ, b_a2h, out, 1);
}

// Round 4
// 390.617 us; speedup vs baseline: 1.3541x; 1.3338x over previous
//
#include <hip/hip_runtime.h>
#include <hip/hip_bf16.h>

#define KDIM 512
#define NDIM 512
#define ATT  196
#define NB   1024

typedef __attribute__((ext_vector_type(8))) short bf16x8;
typedef __attribute__((ext_vector_type(8))) unsigned short ushort8;
typedef __attribute__((ext_vector_type(4))) float f32x4;

typedef const __attribute__((address_space(1))) unsigned int gas_uint;
typedef __attribute__((address_space(3))) unsigned int las_uint;

__device__ __forceinline__ void gload16(const void* g, void* l) {
    __builtin_amdgcn_global_load_lds((gas_uint*)g, (las_uint*)l, 16, 0, 0);
}

__device__ __forceinline__ float fast_tanh(float x) {
    x = fminf(15.f, fmaxf(-15.f, x));
    float t = __expf(2.f * x);
    return (t - 1.f) / (t + 1.f);
}

__device__ __forceinline__ unsigned short f2bf(float x) {
    union { float f; unsigned u; } v; v.f = x;
    unsigned r = v.u + 0x7FFF + ((v.u >> 16) & 1);   // RNE
    return (unsigned short)(r >> 16);
}

__device__ __forceinline__ unsigned pk2(float a, float b) {
    __hip_bfloat162 h = __float22bfloat162_rn(float2{a, b});
    union { __hip_bfloat162 h2; unsigned u; } c; c.h2 = h;
    return c.u;
}

// ---------------------------------------------------------------------------
// Transpose+cast 6 weights: W[k][n] f32 -> Wt[n][k] bf16 ([n][k] row-major).
// ---------------------------------------------------------------------------
__global__ __launch_bounds__(256) void prep_weights(
        const float* __restrict__ W0, const float* __restrict__ W1,
        const float* __restrict__ W2, const float* __restrict__ W3,
        const float* __restrict__ W4, const float* __restrict__ W5,
        unsigned short* __restrict__ Wt) {
    int w = blockIdx.x >> 6;
    int t = blockIdx.x & 63;
    int k0 = (t >> 3) << 6, n0 = (t & 7) << 6;
    const float* W = (w == 0) ? W0 : (w == 1) ? W1 : (w == 2) ? W2 :
                     (w == 3) ? W3 : (w == 4) ? W4 : W5;
    __shared__ float tile[64][65];
    int tid = threadIdx.x;
    int nc = tid & 15, kr = tid >> 4;
#pragma unroll
    for (int i = 0; i < 4; ++i) {
        int k = kr + i * 16;
        float4 v = *(const float4*)&W[(size_t)(k0 + k) * NDIM + n0 + nc * 4];
        tile[k][nc * 4 + 0] = v.x; tile[k][nc * 4 + 1] = v.y;
        tile[k][nc * 4 + 2] = v.z; tile[k][nc * 4 + 3] = v.w;
    }
    __syncthreads();
    int n = tid >> 2, ks = tid & 3;
    ushort8 v0, v1;
#pragma unroll
    for (int j = 0; j < 8; ++j) v0[j] = f2bf(tile[ks * 16 + j][n]);
#pragma unroll
    for (int j = 0; j < 8; ++j) v1[j] = f2bf(tile[ks * 16 + 8 + j][n]);
    size_t base = ((size_t)w << 18) + (size_t)(n0 + n) * KDIM + k0 + ks * 16;
    *(ushort8*)&Wt[base] = v0;
    *(ushort8*)&Wt[base + 8] = v1;
}

// ---------------------------------------------------------------------------
// Small GEMM: out = act(A[1024,512] @ Wt^T + bias). BM=64, BN=128,
// 256 thr = 4 waves (2Mx2N), wave 32x64. Two ops batched via blockIdx.y.
// act: 0=relu 1=tanh 2=none
// ---------------------------------------------------------------------------
__global__ __launch_bounds__(256) void gemm64(
        const float* __restrict__ A0, const unsigned short* __restrict__ W0,
        const float* __restrict__ bia0, float* __restrict__ O0, int act0,
        const float* __restrict__ A1, const unsigned short* __restrict__ W1,
        const float* __restrict__ bia1, float* __restrict__ O1, int act1) {
    const int op = blockIdx.y;
    const float* A = op ? A1 : A0;
    const unsigned short* Bt = op ? W1 : W0;
    const float* bias = op ? bia1 : bia0;
    float* out = op ? O1 : O0;
    const int act = op ? act1 : act0;

    __shared__ unsigned short A_lds[2][64 * 32];
    __shared__ unsigned short B_lds[2][128 * 32];

    const int tid = threadIdx.x;
    const int gm0 = (blockIdx.x >> 2) * 64, gn0 = (blockIdx.x & 3) * 128;
    const int wid = tid >> 6, lane = tid & 63;
    const int wm = wid >> 1, wn = wid & 1;
    const int lr = lane & 15, lk = lane >> 4;

    const int arow = tid >> 2, akc = tid & 3;
    const float* aptr = A + (size_t)(gm0 + arow) * KDIM + akc * 8;
    const int aoff = arow * 32 + ((akc ^ ((arow >> 1) & 3)) << 3);

    auto stageB = [&](int kt, int buf) {
#pragma unroll
        for (int j = 0; j < 2; ++j) {
            int c = tid + j * 256;
            int col = c >> 2, slot = c & 3;
            const unsigned short* src = Bt + (size_t)(gn0 + col) * KDIM +
                                        ((slot ^ ((col >> 1) & 3)) << 3) + kt * 32;
            gload16(src, &B_lds[buf][c * 8]);
        }
    };

    f32x4 acc[2][4] = {};

    {
        float4 x0 = *(const float4*)aptr;
        float4 x1 = *(const float4*)(aptr + 4);
        stageB(0, 0);
        uint4 p;
        p.x = pk2(x0.x, x0.y); p.y = pk2(x0.z, x0.w);
        p.z = pk2(x1.x, x1.y); p.w = pk2(x1.z, x1.w);
        *(uint4*)&A_lds[0][aoff] = p;
    }
    __syncthreads();

    const int swk = ((lk ^ ((lr >> 1) & 3)) << 3);
    for (int kt = 0; kt < 16; ++kt) {
        const int buf = kt & 1;
        float4 x0, x1;
        if (kt < 15) {
            const float* ap = aptr + (kt + 1) * 32;
            x0 = *(const float4*)ap;
            x1 = *(const float4*)(ap + 4);
            stageB(kt + 1, buf ^ 1);
        }
        bf16x8 af[2], bfr[4];
#pragma unroll
        for (int m = 0; m < 2; ++m)
            af[m] = *(const bf16x8*)&A_lds[buf][(wm * 32 + m * 16 + lr) * 32 + swk];
#pragma unroll
        for (int n = 0; n < 4; ++n)
            bfr[n] = *(const bf16x8*)&B_lds[buf][(wn * 64 + n * 16 + lr) * 32 + swk];
#pragma unroll
        for (int m = 0; m < 2; ++m)
#pragma unroll
            for (int n = 0; n < 4; ++n)
                acc[m][n] = __builtin_amdgcn_mfma_f32_16x16x32_bf16(af[m], bfr[n], acc[m][n], 0, 0, 0);
        if (kt < 15) {
            uint4 p;
            p.x = pk2(x0.x, x0.y); p.y = pk2(x0.z, x0.w);
            p.z = pk2(x1.x, x1.y); p.w = pk2(x1.z, x1.w);
            *(uint4*)&A_lds[buf ^ 1][aoff] = p;
        }
        __syncthreads();
    }

#pragma unroll
    for (int m = 0; m < 2; ++m)
#pragma unroll
        for (int n = 0; n < 4; ++n) {
            int col = gn0 + wn * 64 + n * 16 + lr;
            float bsv = bias[col];
#pragma unroll
            for (int r = 0; r < 4; ++r) {
                int row = gm0 + wm * 32 + m * 16 + lk * 4 + r;
                float v = acc[m][n][r] + bsv;
                if (act == 0) v = fmaxf(v, 0.f);
                else if (act == 1) v = fast_tanh(v);
                out[(size_t)row * NDIM + col] = v;
            }
        }
}

// ---------------------------------------------------------------------------
// Score GEMM: A = att [200704, 512] f32, B = W_ctx^T bf16 [n][k].
// BM=BN=128, BK=32, 256 thr = 4 waves (2Mx2N), wave 64x64.
// T14 split: A loads issued at loop top -> regs; consumed (cvt+ds_write)
// AFTER the MFMAs. B staged by global_load_lds (swizzle in source addr).
// Epilogue: per-row partial  sum_col tanh(acc + b_ctx[col] + h_emb[b,col])
//           * Walpha[col]  -> atomicAdd into score[b*197 + pos + 1].
// Grid 6272 = 8 XCDs x 196 mtiles x 4 nblks; N-siblings adjacent per XCD.
// ---------------------------------------------------------------------------
__launch_bounds__(256, 3)
__global__ void gemm_score(const float* __restrict__ A,
                           const unsigned short* __restrict__ Bt,
                           const float* __restrict__ b_ctx,
                           const float* __restrict__ h_emb,
                           const float* __restrict__ Walpha,
                           float* __restrict__ score) {
    __shared__ unsigned short A_lds[2][128 * 32];
    __shared__ unsigned short B_lds[2][128 * 32];
    __shared__ float ch_s[2][128];
    __shared__ float wa_s[128];
    __shared__ float s_red[2][128];

    const int tid  = threadIdx.x;
    const int bidx = blockIdx.x;
    const int xcd  = bidx & 7, u = bidx >> 3;
    const int mblk = xcd * 196 + (u >> 2), nblk = u & 3;
    const int gm0  = mblk * 128, gn0 = nblk * 128;

    const int wid = tid >> 6, lane = tid & 63;
    const int wm  = wid >> 1, wn = wid & 1;
    const int lr  = lane & 15, lk = lane >> 4;

    const int b0 = gm0 / ATT;           // first batch covered by this block
    // prologue: ch (b_ctx + h_emb) for the <=2 batches, Walpha slice
    {
        int j = tid >> 7, cloc = tid & 127;
        int bb = b0 + j; if (bb > NB - 1) bb = NB - 1;
        ch_s[j][cloc] = b_ctx[gn0 + cloc] + h_emb[(size_t)bb * NDIM + gn0 + cloc];
        if (tid < 128) wa_s[tid] = Walpha[gn0 + tid];
    }

    // A staging: thread -> row=tid>>1, half=tid&1 (16 f32 -> 2 bf16 chunks)
    const int arow = tid >> 1, ahalf = tid & 1;
    const float* aptr = A + (size_t)(gm0 + arow) * KDIM + ahalf * 16;
    const int skc0  = (ahalf * 2) ^ ((arow >> 1) & 3);
    const int aoff0 = arow * 32 + skc0 * 8;
    const int aoff1 = arow * 32 + (skc0 ^ 1) * 8;

    auto stageB = [&](int kt, int buf) {
#pragma unroll
        for (int j = 0; j < 2; ++j) {
            int c = tid + j * 256;
            int col = c >> 2, slot = c & 3;
            const unsigned short* src = Bt + (size_t)(gn0 + col) * KDIM +
                                        ((slot ^ ((col >> 1) & 3)) << 3) + kt * 32;
            gload16(src, &B_lds[buf][c * 8]);
        }
    };

    f32x4 acc[4][4] = {};

    // prologue stage kt=0
    {
        float4 x0 = *(const float4*)(aptr);
        float4 x1 = *(const float4*)(aptr + 4);
        float4 x2 = *(const float4*)(aptr + 8);
        float4 x3 = *(const float4*)(aptr + 12);
        stageB(0, 0);
        uint4 p0, p1;
        p0.x = pk2(x0.x, x0.y); p0.y = pk2(x0.z, x0.w);
        p0.z = pk2(x1.x, x1.y); p0.w = pk2(x1.z, x1.w);
        p1.x = pk2(x2.x, x2.y); p1.y = pk2(x2.z, x2.w);
        p1.z = pk2(x3.x, x3.y); p1.w = pk2(x3.z, x3.w);
        *(uint4*)&A_lds[0][aoff0] = p0;
        *(uint4*)&A_lds[0][aoff1] = p1;
    }
    __syncthreads();

    const int swk = ((lk ^ ((lr >> 1) & 3)) << 3);
    for (int kt = 0; kt < 16; ++kt) {
        const int buf = kt & 1;
        float4 x0, x1, x2, x3;
        if (kt < 15) {
            const float* ap = aptr + (kt + 1) * 32;
            x0 = *(const float4*)(ap);
            x1 = *(const float4*)(ap + 4);
            x2 = *(const float4*)(ap + 8);
            x3 = *(const float4*)(ap + 12);
            stageB(kt + 1, buf ^ 1);
        }
        bf16x8 af[4], bfr[4];
#pragma unroll
        for (int m = 0; m < 4; ++m)
            af[m] = *(const bf16x8*)&A_lds[buf][(wm * 64 + m * 16 + lr) * 32 + swk];
#pragma unroll
        for (int n = 0; n < 4; ++n)
            bfr[n] = *(const bf16x8*)&B_lds[buf][(wn * 64 + n * 16 + lr) * 32 + swk];
#pragma unroll
        for (int m = 0; m < 4; ++m)
#pragma unroll
            for (int n = 0; n < 4; ++n)
                acc[m][n] = __builtin_amdgcn_mfma_f32_16x16x32_bf16(af[m], bfr[n], acc[m][n], 0, 0, 0);
        if (kt < 15) {
            uint4 p0, p1;
            p0.x = pk2(x0.x, x0.y); p0.y = pk2(x0.z, x0.w);
            p0.z = pk2(x1.x, x1.y); p0.w = pk2(x1.z, x1.w);
            p1.x = pk2(x2.x, x2.y); p1.y = pk2(x2.z, x2.w);
            p1.z = pk2(x3.x, x3.y); p1.w = pk2(x3.z, x3.w);
            *(uint4*)&A_lds[buf ^ 1][aoff0] = p0;
            *(uint4*)&A_lds[buf ^ 1][aoff1] = p1;
        }
        __syncthreads();
    }

    // epilogue: per-row partial score
    const int bsplit = (b0 + 1) * ATT;
#pragma unroll
    for (int m = 0; m < 4; ++m) {
#pragma unroll
        for (int r = 0; r < 4; ++r) {
            int rloc = wm * 64 + m * 16 + lk * 4 + r;
            int rg = gm0 + rloc;
            int sel = (rg >= bsplit) ? 1 : 0;
            float sum = 0.f;
#pragma unroll
            for (int n = 0; n < 4; ++n) {
                int cloc = wn * 64 + n * 16 + lr;
                sum += fast_tanh(acc[m][n][r] + ch_s[sel][cloc]) * wa_s[cloc];
            }
            sum += __shfl_xor(sum, 1);
            sum += __shfl_xor(sum, 2);
            sum += __shfl_xor(sum, 4);
            sum += __shfl_xor(sum, 8);
            if (lr == 0) s_red[wn][rloc] = sum;
        }
    }
    __syncthreads();
    if (tid < 128) {
        float tot = s_red[0][tid] + s_red[1][tid];
        int rg = gm0 + tid;
        int sel = (rg >= bsplit) ? 1 : 0;
        int bb = b0 + sel;
        atomicAdd(&score[(size_t)bb * 197 + (rg - bb * ATT) + 1], tot);
    }
}

// ---------------------------------------------------------------------------
// Per-batch: sentinel score (pos 0) from sent_emb+h_emb, softmax over 197,
// atten_out[b,:] = al0*sent_lin + sum_s al[s+1]*att[b,s,:] + h_lin
// ---------------------------------------------------------------------------
__global__ __launch_bounds__(256) void softmax_chat(
        const float* __restrict__ score, const float* __restrict__ sent_emb,
        const float* __restrict__ h_emb, const float* __restrict__ Walpha,
        const float* __restrict__ sent_lin, const float* __restrict__ h_lin,
        const float* __restrict__ att, float* __restrict__ atten_out) {
    int b = blockIdx.x, tid = threadIdx.x;
    __shared__ float al[200];
    __shared__ float r4[4];

    // sentinel score: sum_c tanh(sent_emb+h_emb)*wa, 256 thr x float2
    float2 se = ((const float2*)(sent_emb + (size_t)b * NDIM))[tid];
    float2 he = ((const float2*)(h_emb + (size_t)b * NDIM))[tid];
    float2 wa = ((const float2*)Walpha)[tid];
    float val = fast_tanh(se.x + he.x) * wa.x + fast_tanh(se.y + he.y) * wa.y;
#pragma unroll
    for (int o = 32; o; o >>= 1) val += __shfl_xor(val, o);
    if ((tid & 63) == 0) r4[tid >> 6] = val;
    __syncthreads();
    float ssent = r4[0] + r4[1] + r4[2] + r4[3];
    __syncthreads();

    float v = -1e30f;
    if (tid < 197) v = (tid == 0) ? ssent : score[(size_t)b * 197 + tid];
    float m = v;
#pragma unroll
    for (int o = 32; o; o >>= 1) m = fmaxf(m, __shfl_xor(m, o));
    if ((tid & 63) == 0) r4[tid >> 6] = m;
    __syncthreads();
    m = fmaxf(fmaxf(r4[0], r4[1]), fmaxf(r4[2], r4[3]));
    __syncthreads();
    float e = (tid < 197) ? __expf(v - m) : 0.f;
    float s = e;
#pragma unroll
    for (int o = 32; o; o >>= 1) s += __shfl_xor(s, o);
    if ((tid & 63) == 0) r4[tid >> 6] = s;
    __syncthreads();
    s = r4[0] + r4[1] + r4[2] + r4[3];
    if (tid < 197) al[tid] = e / s;
    __syncthreads();

    const float2* af = (const float2*)(att + (size_t)b * ATT * KDIM);
    float2 a0 = ((const float2*)(sent_lin + (size_t)b * KDIM))[tid];
    float w0 = al[0];
    float2 accv; accv.x = w0 * a0.x; accv.y = w0 * a0.y;
#pragma unroll 14
    for (int ss = 0; ss < ATT; ++ss) {
        float w = al[ss + 1];
        float2 x = af[(size_t)ss * 256 + tid];
        accv.x += w * x.x; accv.y += w * x.y;
    }
    float2 hl = ((const float2*)(h_lin + (size_t)b * KDIM))[tid];
    accv.x += hl.x; accv.y += hl.y;
    ((float2*)(atten_out + (size_t)b * KDIM))[tid] = accv;
}

// ---------------------------------------------------------------------------
extern "C" void kernel_launch(void* const* d_in, const int* in_sizes, int n_in,
                              void* d_out, int out_size, void* d_ws, size_t ws_size,
                              hipStream_t stream) {
    const float* h     = (const float*)d_in[0];
    const float* sent  = (const float*)d_in[1];
    const float* att   = (const float*)d_in[2];
    const float* W_ctx = (const float*)d_in[3];
    const float* b_ctx = (const float*)d_in[4];
    const float* W_sl  = (const float*)d_in[5];
    const float* b_sl  = (const float*)d_in[6];
    const float* W_se  = (const float*)d_in[7];
    const float* b_se  = (const float*)d_in[8];
    const float* W_hl  = (const float*)d_in[9];
    const float* b_hl  = (const float*)d_in[10];
    const float* W_he  = (const float*)d_in[11];
    const float* b_he  = (const float*)d_in[12];
    const float* W_al  = (const float*)d_in[13];
    // d_in[14] = b_alpha: constant across positions, cancels in softmax
    const float* W_a2h = (const float*)d_in[15];
    const float* b_a2h = (const float*)d_in[16];
    float* out = (float*)d_out;

    char* ws = (char*)d_ws;
    unsigned short* Wt = (unsigned short*)ws;                 // 6 * 512KB bf16 = 3MB
    float* sent_lin = (float*)(ws + 6u * 512 * 1024);
    float* h_lin    = sent_lin + (size_t)NB * 512;
    float* h_emb    = h_lin    + (size_t)NB * 512;
    float* sent_emb = h_emb    + (size_t)NB * 512;
    float* scorebuf = sent_emb + (size_t)NB * 512;            // 1024*197
    float* atten    = scorebuf + (size_t)NB * 197;

    const size_t WSZ = 512 * 512;  // ushorts per weight
    // Wt order: 0=W_sl 1=W_hl 2=W_he 3=W_ctx 4=W_a2h 5=W_se
    prep_weights<<<384, 256, 0, stream>>>(W_sl, W_hl, W_he, W_ctx, W_a2h, W_se, Wt);
    hipMemsetAsync(scorebuf, 0, (size_t)NB * 197 * sizeof(float), stream);

    // sent_lin = relu(sent@W_sl+b_sl); h_lin = tanh(h@W_hl+b_hl)
    gemm64<<<dim3(64, 2), 256, 0, stream>>>(
        sent, Wt + 0 * WSZ, b_sl, sent_lin, 0,
        h,    Wt + 1 * WSZ, b_hl, h_lin,    1);
    // h_emb = h_lin@W_he+b_he; sent_emb = sent_lin@W_se+b_se
    gemm64<<<dim3(64, 2), 256, 0, stream>>>(
        h_lin,    Wt + 2 * WSZ, b_he, h_emb,    2,
        sent_lin, Wt + 5 * WSZ, b_se, sent_emb, 2);

    // visual scores -> scorebuf[b*197 + 1 + s]
    gemm_score<<<6272, 256, 0, stream>>>(att, Wt + 3 * WSZ, b_ctx, h_emb, W_al, scorebuf);

    softmax_chat<<<NB, 256, 0, stream>>>(scorebuf, sent_emb, h_emb, W_al,
                                         sent_lin, h_lin, att, atten);

    // out = tanh(atten@W_a2h + b_a2h)
    gemm64<<<dim3(64, 1), 256, 0, stream>>>(
        atten, Wt + 4 * WSZ, b_a2h, out, 1,
        atten, Wt + 4 * WSZ, b_a2h, out, 1);
}